// Round 1
// baseline (1851.991 us; speedup 1.0000x reference)
//
#include <hip/hip_runtime.h>

#define NN 50000
#define EE 800000
#define HD 256

typedef __bf16 bf16;
typedef bf16 bf16x8 __attribute__((ext_vector_type(8)));
typedef bf16 bf16x4 __attribute__((ext_vector_type(4)));
typedef float f32x4 __attribute__((ext_vector_type(4)));

__device__ __forceinline__ float silu_f(float v) { return v / (1.f + __expf(-v)); }

// packed-weight linear index -> (k, col). Layout: [kc][nc][lane][r], r=0..7
__device__ __forceinline__ void pk_idx(int p, int& k, int& col) {
  int r = p & 7;
  int lane = (p >> 3) & 63;
  int nc = (p >> 9) & 15;
  int kc = p >> 13;
  k = kc * 32 + ((lane >> 4) << 3) + r;
  col = (nc << 4) + (lane & 15);
}

// ---------------- prep: zero m_i, copy x->xout, pack weights to bf16 fragments ----
__global__ __launch_bounds__(256) void prep_kernel(
    const float* __restrict__ x,
    const float* __restrict__ We1, const float* __restrict__ We2,
    const float* __restrict__ Wc1, const float* __restrict__ Wn1,
    const float* __restrict__ Wn2,
    float* __restrict__ m_i, float* __restrict__ xout,
    bf16* __restrict__ We1p, bf16* __restrict__ We2p, bf16* __restrict__ Wc1p,
    bf16* __restrict__ Wn1p, bf16* __restrict__ Wn2p)
{
  const int stride = gridDim.x * blockDim.x;
  for (int i = blockIdx.x * blockDim.x + threadIdx.x; i < NN * HD; i += stride) {
    m_i[i] = 0.f;
    if (i < 3 * NN) xout[i] = x[i];
    if (i < 19 * 8192) {  // We1 packed: K-order = h_src(256) h_dst(256) ea(64) dsq(1) zeros(31)
      int k, col; pk_idx(i, k, col);
      float v = 0.f;
      if (k < 512) v = We1[k * HD + col];
      else if (k < 576) v = We1[(k + 1) * HD + col];  // edge_attr rows 513..576
      else if (k == 576) v = We1[512 * HD + col];     // dist_sq row
      We1p[i] = (bf16)v;
    }
    if (i < 8 * 8192) {
      int k, col; pk_idx(i, k, col);
      We2p[i] = (bf16)We2[k * HD + col];
      Wc1p[i] = (bf16)Wc1[k * HD + col];
      Wn2p[i] = (bf16)Wn2[k * HD + col];
    }
    if (i < 16 * 8192) {
      int k, col; pk_idx(i, k, col);
      Wn1p[i] = (bf16)Wn1[k * HD + col];
    }
  }
}

__device__ __forceinline__ void zero_acc(f32x4 acc[2][4]) {
#pragma unroll
  for (int m = 0; m < 2; ++m)
#pragma unroll
    for (int t = 0; t < 4; ++t)
#pragma unroll
      for (int r = 0; r < 4; ++r) acc[m][t][r] = 0.f;
}

// 32 rows (2 M-tiles) x 64 cols (4 N-tiles per wave) GEMM step.
// A layout: row = lane&15, k = (lane>>4)*8 + r  (LDS, pitch = odd*16B)
// B layout: packed [kc][nc][lane][8] -> one 16B load per fragment
template <int KC>
__device__ __forceinline__ void mm_layer(const bf16* __restrict__ Asrc, int pitch,
                                         const bf16* __restrict__ Wp, int lane, int nc0,
                                         f32x4 acc[2][4])
{
  const int la = lane & 15, lb = lane >> 4;
#pragma unroll 1
  for (int kc = 0; kc < KC; ++kc) {
    bf16x8 a0 = *(const bf16x8*)&Asrc[la * pitch + kc * 32 + lb * 8];
    bf16x8 a1 = *(const bf16x8*)&Asrc[(16 + la) * pitch + kc * 32 + lb * 8];
    const bf16x8* wp = (const bf16x8*)Wp + ((kc * 16 + nc0) * 64 + lane);
#pragma unroll
    for (int t = 0; t < 4; ++t) {
      bf16x8 b = wp[t * 64];
      acc[0][t] = __builtin_amdgcn_mfma_f32_16x16x32_bf16(a0, b, acc[0][t], 0, 0, 0);
      acc[1][t] = __builtin_amdgcn_mfma_f32_16x16x32_bf16(a1, b, acc[1][t], 0, 0, 0);
    }
  }
}

constexpr int EB = 32;
constexpr int EIN_P = 616;  // 608 used + pad -> 1232B = 77*16B (odd) : conflict-free b128
constexpr int T1_P = 264;   // 528B = 33*16B (odd)

// ---------------- edge kernel: 3 fused GEMM layers + scatters --------------------
__global__ __launch_bounds__(256) void edge_kernel(
    const float* __restrict__ h, const float* __restrict__ x,
    const int* __restrict__ ei, const float* __restrict__ ea,
    const bf16* __restrict__ We1p, const float* __restrict__ be1,
    const bf16* __restrict__ We2p, const float* __restrict__ be2,
    const bf16* __restrict__ Wc1p, const float* __restrict__ bc1,
    const float* __restrict__ Wc2,
    float* __restrict__ m_i, float* __restrict__ xout)
{
  __shared__ __align__(16) bf16 ein[EB * EIN_P];
  __shared__ __align__(16) bf16 t1s[EB * T1_P];
  __shared__ __align__(16) bf16 mjs[EB * T1_P];
  __shared__ float rel0[EB], rel1[EB], rel2[EB];
  __shared__ float cw[EB];
  __shared__ int sidx[EB], didx[EB];

  const int tid = threadIdx.x;
  const int e0 = blockIdx.x * EB;

  if (tid < EB) {
    int e = e0 + tid;
    int s = ei[e], d = ei[EE + e];
    sidx[tid] = s; didx[tid] = d;
    float rx = x[3 * s + 0] - x[3 * d + 0];
    float ry = x[3 * s + 1] - x[3 * d + 1];
    float rz = x[3 * s + 2] - x[3 * d + 2];
    rel0[tid] = rx; rel1[tid] = ry; rel2[tid] = rz;
    float dsq = rx * rx + ry * ry + rz * rz;
    ein[tid * EIN_P + 576] = (bf16)dsq;
    for (int k2 = 577; k2 < 608; ++k2) ein[tid * EIN_P + k2] = (bf16)0.f;
    cw[tid] = 0.f;
  }
  __syncthreads();

  // gather h[src] | h[dst] | edge_attr -> bf16 LDS
  for (int i = tid; i < EB * 64; i += 256) {
    int er = i >> 6, q = i & 63;
    float4 v = ((const float4*)h)[(long)sidx[er] * 64 + q];
    bf16x4 b; b[0] = (bf16)v.x; b[1] = (bf16)v.y; b[2] = (bf16)v.z; b[3] = (bf16)v.w;
    *(bf16x4*)&ein[er * EIN_P + q * 4] = b;
  }
  for (int i = tid; i < EB * 64; i += 256) {
    int er = i >> 6, q = i & 63;
    float4 v = ((const float4*)h)[(long)didx[er] * 64 + q];
    bf16x4 b; b[0] = (bf16)v.x; b[1] = (bf16)v.y; b[2] = (bf16)v.z; b[3] = (bf16)v.w;
    *(bf16x4*)&ein[er * EIN_P + 256 + q * 4] = b;
  }
  for (int i = tid; i < EB * 16; i += 256) {
    int er = i >> 4, q = i & 15;
    float4 v = ((const float4*)ea)[(long)(e0 + er) * 16 + q];
    bf16x4 b; b[0] = (bf16)v.x; b[1] = (bf16)v.y; b[2] = (bf16)v.z; b[3] = (bf16)v.w;
    *(bf16x4*)&ein[er * EIN_P + 512 + q * 4] = b;
  }
  __syncthreads();

  const int lane = tid & 63;
  const int wv = tid >> 6;
  const int la = lane & 15, lb = lane >> 4;
  const int nc0 = wv * 4;  // each wave owns a distinct 64-col quarter

  f32x4 acc[2][4];
  zero_acc(acc);
  mm_layer<19>(ein, EIN_P, We1p, lane, nc0, acc);
#pragma unroll
  for (int t = 0; t < 4; ++t) {
    int col = (nc0 + t) * 16 + la;
    float bias = be1[col];
#pragma unroll
    for (int m = 0; m < 2; ++m)
#pragma unroll
      for (int r = 0; r < 4; ++r) {
        int row = m * 16 + lb * 4 + r;
        t1s[row * T1_P + col] = (bf16)silu_f(acc[m][t][r] + bias);
      }
  }
  __syncthreads();

  zero_acc(acc);
  mm_layer<8>(t1s, T1_P, We2p, lane, nc0, acc);
  int dr[2][4];
#pragma unroll
  for (int m = 0; m < 2; ++m)
#pragma unroll
    for (int r = 0; r < 4; ++r) dr[m][r] = didx[m * 16 + lb * 4 + r];
#pragma unroll
  for (int t = 0; t < 4; ++t) {
    int col = (nc0 + t) * 16 + la;
    float bias = be2[col];
#pragma unroll
    for (int m = 0; m < 2; ++m)
#pragma unroll
      for (int r = 0; r < 4; ++r) {
        int row = m * 16 + lb * 4 + r;
        float mv = silu_f(acc[m][t][r] + bias);
        mjs[row * T1_P + col] = (bf16)mv;
        atomicAdd(&m_i[(long)dr[m][r] * HD + col], mv);
      }
  }
  __syncthreads();

  zero_acc(acc);
  mm_layer<8>(mjs, T1_P, Wc1p, lane, nc0, acc);
  float pr[2][4];
#pragma unroll
  for (int m = 0; m < 2; ++m)
#pragma unroll
    for (int r = 0; r < 4; ++r) pr[m][r] = 0.f;
#pragma unroll
  for (int t = 0; t < 4; ++t) {
    int col = (nc0 + t) * 16 + la;
    float bias = bc1[col];
    float wc = Wc2[col];
#pragma unroll
    for (int m = 0; m < 2; ++m)
#pragma unroll
      for (int r = 0; r < 4; ++r)
        pr[m][r] += silu_f(acc[m][t][r] + bias) * wc;
  }
#pragma unroll
  for (int m = 0; m < 2; ++m)
#pragma unroll
    for (int r = 0; r < 4; ++r) {
      float v = pr[m][r];
      v += __shfl_xor(v, 1);
      v += __shfl_xor(v, 2);
      v += __shfl_xor(v, 4);
      v += __shfl_xor(v, 8);
      if (la == 0) atomicAdd(&cw[m * 16 + lb * 4 + r], v);
    }
  __syncthreads();

  if (tid < EB) {
    float wgt = cw[tid];
    int d = didx[tid];
    atomicAdd(&xout[3 * d + 0], rel0[tid] * wgt);
    atomicAdd(&xout[3 * d + 1], rel1[tid] * wgt);
    atomicAdd(&xout[3 * d + 2], rel2[tid] * wgt);
  }
}

constexpr int NB = 32;
constexpr int NIN_P = 520;  // 1040B = 65*16B (odd)

// ---------------- node kernel: h_out = h + node_mlp([h, m_i]) --------------------
__global__ __launch_bounds__(256) void node_kernel(
    const float* __restrict__ h, const float* __restrict__ m_i,
    const bf16* __restrict__ Wn1p, const float* __restrict__ bn1,
    const bf16* __restrict__ Wn2p, const float* __restrict__ bn2,
    float* __restrict__ hout)
{
  __shared__ __align__(16) bf16 nin[NB * NIN_P];
  __shared__ __align__(16) bf16 tls[NB * T1_P];
  const int tid = threadIdx.x;
  const long n0 = (long)blockIdx.x * NB;

  for (int i = tid; i < NB * 64; i += 256) {
    int nr = i >> 6, q = i & 63;
    long row = n0 + nr; if (row >= NN) row = NN - 1;
    float4 v = ((const float4*)h)[row * 64 + q];
    bf16x4 b; b[0] = (bf16)v.x; b[1] = (bf16)v.y; b[2] = (bf16)v.z; b[3] = (bf16)v.w;
    *(bf16x4*)&nin[nr * NIN_P + q * 4] = b;
    float4 u = ((const float4*)m_i)[row * 64 + q];
    bf16x4 c; c[0] = (bf16)u.x; c[1] = (bf16)u.y; c[2] = (bf16)u.z; c[3] = (bf16)u.w;
    *(bf16x4*)&nin[nr * NIN_P + 256 + q * 4] = c;
  }
  __syncthreads();

  const int lane = tid & 63;
  const int wv = tid >> 6;
  const int la = lane & 15, lb = lane >> 4;
  const int nc0 = wv * 4;

  f32x4 acc[2][4];
  zero_acc(acc);
  mm_layer<16>(nin, NIN_P, Wn1p, lane, nc0, acc);
#pragma unroll
  for (int t = 0; t < 4; ++t) {
    int col = (nc0 + t) * 16 + la;
    float bias = bn1[col];
#pragma unroll
    for (int m = 0; m < 2; ++m)
#pragma unroll
      for (int r = 0; r < 4; ++r) {
        int row = m * 16 + lb * 4 + r;
        tls[row * T1_P + col] = (bf16)silu_f(acc[m][t][r] + bias);
      }
  }
  __syncthreads();

  zero_acc(acc);
  mm_layer<8>(tls, T1_P, Wn2p, lane, nc0, acc);
#pragma unroll
  for (int t = 0; t < 4; ++t) {
    int col = (nc0 + t) * 16 + la;
    float bias = bn2[col];
#pragma unroll
    for (int m = 0; m < 2; ++m)
#pragma unroll
      for (int r = 0; r < 4; ++r) {
        long row = n0 + m * 16 + lb * 4 + r;
        if (row < NN)
          hout[row * HD + col] = h[row * HD + col] + acc[m][t][r] + bias;
      }
  }
}

extern "C" void kernel_launch(void* const* d_in, const int* in_sizes, int n_in,
                              void* d_out, int out_size, void* d_ws, size_t ws_size,
                              hipStream_t stream) {
  (void)in_sizes; (void)n_in; (void)out_size; (void)ws_size;
  const float* h   = (const float*)d_in[0];
  const float* x   = (const float*)d_in[1];
  const int*   ei  = (const int*)d_in[2];
  const float* ea  = (const float*)d_in[3];
  const float* We1 = (const float*)d_in[4];
  const float* be1 = (const float*)d_in[5];
  const float* We2 = (const float*)d_in[6];
  const float* be2 = (const float*)d_in[7];
  const float* Wn1 = (const float*)d_in[8];
  const float* bn1 = (const float*)d_in[9];
  const float* Wn2 = (const float*)d_in[10];
  const float* bn2 = (const float*)d_in[11];
  const float* Wc1 = (const float*)d_in[12];
  const float* bc1 = (const float*)d_in[13];
  const float* Wc2 = (const float*)d_in[14];

  float* hout = (float*)d_out;
  float* xout = hout + (long)NN * HD;

  char* ws = (char*)d_ws;
  float* m_i = (float*)ws;                       // 51,200,000 B
  bf16* We1p = (bf16*)(ws + 51200000);           // 311,296 B
  bf16* We2p = (bf16*)(ws + 51511296);           // 131,072 B
  bf16* Wc1p = (bf16*)(ws + 51642368);           // 131,072 B
  bf16* Wn1p = (bf16*)(ws + 51773440);           // 262,144 B
  bf16* Wn2p = (bf16*)(ws + 52035584);           // 131,072 B

  prep_kernel<<<2048, 256, 0, stream>>>(x, We1, We2, Wc1, Wn1, Wn2,
                                        m_i, xout, We1p, We2p, Wc1p, Wn1p, Wn2p);
  edge_kernel<<<EE / EB, 256, 0, stream>>>(h, x, ei, ea, We1p, be1, We2p, be2,
                                           Wc1p, bc1, Wc2, m_i, xout);
  node_kernel<<<(NN + NB - 1) / NB, 256, 0, stream>>>(h, m_i, Wn1p, bn1, Wn2p, bn2, hout);
}